// Round 3
// baseline (2129.017 us; speedup 1.0000x reference)
//
#include <hip/hip_runtime.h>
#include <hip/hip_bf16.h>

#define D1 8
#define RANK 8
#define ROWS 2   // rows per thread: halves DS-read count, state small enough to stay in VGPRs

__global__ __launch_bounds__(256) void tt_poly_kernel(
    const float* __restrict__ X,
    const float* __restrict__ G0,   // [d1, r]
    const float* __restrict__ G1,   // [r, d1, r]
    const float* __restrict__ G2,   // [r, d1, r]
    const float* __restrict__ G3,   // [r, d1]
    float* __restrict__ out,
    int B, int S)
{
    // ---- stage all coefficients into LDS (4.6 KB), one time per block ----
    __shared__ float sG0[D1 * RANK];         // [d][r]   contiguous in r
    __shared__ float sG1[RANK * D1 * RANK];  // [r][d][s] contiguous in s
    __shared__ float sG2[RANK * D1 * RANK];
    __shared__ float sG3T[D1 * RANK];        // transposed: [d][t]

    const int tid = threadIdx.x;
    if (tid < 128)
        reinterpret_cast<float4*>(sG1)[tid] = reinterpret_cast<const float4*>(G1)[tid];
    else
        reinterpret_cast<float4*>(sG2)[tid - 128] = reinterpret_cast<const float4*>(G2)[tid - 128];
    if (tid < 16)
        reinterpret_cast<float4*>(sG0)[tid] = reinterpret_cast<const float4*>(G0)[tid];
    else if (tid < 80) {
        int i = tid - 16;                     // i = t*8 + d (flat G3 index)
        sG3T[(i & 7) * RANK + (i >> 3)] = G3[i];
    }
    __syncthreads();

    const int gid = blockIdx.x * blockDim.x + tid;

    float4 x[ROWS];
    #pragma unroll
    for (int k = 0; k < ROWS; ++k) {
        int b = gid + k * S;
        x[k] = (b < B) ? reinterpret_cast<const float4*>(X)[b]
                       : make_float4(0.f, 0.f, 0.f, 0.f);
    }

    // ---- stage 1: t0[k][r] = sum_d x0^d G0[d][r], Horner over d ----
    float t0[ROWS][RANK];
    {
        #pragma unroll
        for (int k = 0; k < ROWS; ++k)
            #pragma unroll
            for (int r = 0; r < RANK; ++r)
                t0[k][r] = sG0[(D1 - 1) * RANK + r];
        #pragma unroll
        for (int d = D1 - 2; d >= 0; --d) {
            #pragma unroll
            for (int k = 0; k < ROWS; ++k)
                #pragma unroll
                for (int r = 0; r < RANK; ++r)
                    t0[k][r] = fmaf(t0[k][r], x[k].x, sG0[d * RANK + r]);
        }
    }

    // ---- stage 2: t1[k][s] = sum_{r,d} t0[k][r] G1[r][d][s] x1^d (Horner over d) ----
    float t1[ROWS][RANK];
    {
        #pragma unroll
        for (int dd = 0; dd < D1; ++dd) {
            const int d = D1 - 1 - dd;
            float c[ROWS][RANK];
            #pragma unroll
            for (int k = 0; k < ROWS; ++k)
                #pragma unroll
                for (int s = 0; s < RANK; ++s) c[k][s] = 0.f;
            #pragma unroll
            for (int r = 0; r < RANK; ++r) {
                const float* g = &sG1[(r * D1 + d) * RANK];
                #pragma unroll
                for (int k = 0; k < ROWS; ++k)
                    #pragma unroll
                    for (int s = 0; s < RANK; ++s)
                        c[k][s] = fmaf(t0[k][r], g[s], c[k][s]);
            }
            if (dd == 0) {
                #pragma unroll
                for (int k = 0; k < ROWS; ++k)
                    #pragma unroll
                    for (int s = 0; s < RANK; ++s) t1[k][s] = c[k][s];
            } else {
                #pragma unroll
                for (int k = 0; k < ROWS; ++k)
                    #pragma unroll
                    for (int s = 0; s < RANK; ++s)
                        t1[k][s] = fmaf(t1[k][s], x[k].y, c[k][s]);
            }
        }
    }

    // ---- stage 3: same with G2, x2 ----
    float t2[ROWS][RANK];
    {
        #pragma unroll
        for (int dd = 0; dd < D1; ++dd) {
            const int d = D1 - 1 - dd;
            float c[ROWS][RANK];
            #pragma unroll
            for (int k = 0; k < ROWS; ++k)
                #pragma unroll
                for (int s = 0; s < RANK; ++s) c[k][s] = 0.f;
            #pragma unroll
            for (int r = 0; r < RANK; ++r) {
                const float* g = &sG2[(r * D1 + d) * RANK];
                #pragma unroll
                for (int k = 0; k < ROWS; ++k)
                    #pragma unroll
                    for (int s = 0; s < RANK; ++s)
                        c[k][s] = fmaf(t1[k][r], g[s], c[k][s]);
            }
            if (dd == 0) {
                #pragma unroll
                for (int k = 0; k < ROWS; ++k)
                    #pragma unroll
                    for (int s = 0; s < RANK; ++s) t2[k][s] = c[k][s];
            } else {
                #pragma unroll
                for (int k = 0; k < ROWS; ++k)
                    #pragma unroll
                    for (int s = 0; s < RANK; ++s)
                        t2[k][s] = fmaf(t2[k][s], x[k].z, c[k][s]);
            }
        }
    }

    // ---- stage 4: res[k] = sum_{t,d} t2[k][t] G3[t][d] x3^d, Horner over d ----
    float res[ROWS];
    #pragma unroll
    for (int k = 0; k < ROWS; ++k) res[k] = 0.f;
    #pragma unroll
    for (int dd = 0; dd < D1; ++dd) {
        const int d = D1 - 1 - dd;
        const float* g = &sG3T[d * RANK];    // contiguous in t
        #pragma unroll
        for (int k = 0; k < ROWS; ++k) {
            float e = 0.f;
            #pragma unroll
            for (int t = 0; t < RANK; ++t)
                e = fmaf(t2[k][t], g[t], e);
            res[k] = fmaf(res[k], x[k].w, e);
        }
    }

    #pragma unroll
    for (int k = 0; k < ROWS; ++k) {
        int b = gid + k * S;
        if (b < B) out[b] = res[k];
    }
}

extern "C" void kernel_launch(void* const* d_in, const int* in_sizes, int n_in,
                              void* d_out, int out_size, void* d_ws, size_t ws_size,
                              hipStream_t stream) {
    const float* X  = (const float*)d_in[0];
    const float* G0 = (const float*)d_in[1];
    const float* G1 = (const float*)d_in[2];
    const float* G2 = (const float*)d_in[3];
    const float* G3 = (const float*)d_in[4];
    float* out = (float*)d_out;

    int B = in_sizes[0] / 4;   // X is [B,4]
    int block = 256;
    int grid = (B + block * ROWS - 1) / (block * ROWS);
    int S = grid * block;
    tt_poly_kernel<<<grid, block, 0, stream>>>(X, G0, G1, G2, G3, out, B, S);
}

// Round 4
// 66.463 us; speedup vs baseline: 32.0331x; 32.0331x over previous
//
#include <hip/hip_runtime.h>
#include <hip/hip_bf16.h>

#define D1 8
#define RANK 8
#define ROWS 4   // rows/thread: each 64-float LDS coeff block read once per 4 rows

__global__ __launch_bounds__(256) void tt_poly_kernel(
    const float* __restrict__ X,
    const float* __restrict__ G0,   // [d1, r]
    const float* __restrict__ G1,   // [r, d1, s]
    const float* __restrict__ G2,   // [r, d1, s]
    const float* __restrict__ G3,   // [t, d1]
    float* __restrict__ out,
    int B, int S)
{
    __shared__ float sG0[D1 * RANK];          // [d][r]
    __shared__ float sG1[RANK * D1 * RANK];   // [r][d][s] -> idx r*64 + d*8 + s
    __shared__ float sG2[RANK * D1 * RANK];
    __shared__ float sG3T[D1 * RANK];         // [d][t]

    const int tid = threadIdx.x;
    if (tid < 128)
        reinterpret_cast<float4*>(sG1)[tid] = reinterpret_cast<const float4*>(G1)[tid];
    else
        reinterpret_cast<float4*>(sG2)[tid - 128] = reinterpret_cast<const float4*>(G2)[tid - 128];
    if (tid < 16)
        reinterpret_cast<float4*>(sG0)[tid] = reinterpret_cast<const float4*>(G0)[tid];
    else if (tid < 80) {
        int i = tid - 16;                     // i = t*8 + d
        sG3T[(i & 7) * RANK + (i >> 3)] = G3[i];
    }
    __syncthreads();

    const int gid = blockIdx.x * blockDim.x + tid;

    float4 x[ROWS];
    #pragma unroll
    for (int k = 0; k < ROWS; ++k) {
        int b = gid + k * S;
        x[k] = (b < B) ? reinterpret_cast<const float4*>(X)[b]
                       : make_float4(0.f, 0.f, 0.f, 0.f);
    }

    float a[ROWS][RANK];   // stage outputs / inputs (double duty)
    float b[ROWS][RANK];
    float xp[ROWS];

    // ---- stage 1: a[k][r] = sum_d x0^d * G0[d][r]  (rolled over d) ----
    #pragma unroll
    for (int k = 0; k < ROWS; ++k) {
        xp[k] = 1.f;
        #pragma unroll
        for (int r = 0; r < RANK; ++r) a[k][r] = 0.f;
    }
    #pragma unroll 1
    for (int d = 0; d < D1; ++d) {
        const float* g = &sG0[d * RANK];
        #pragma unroll
        for (int k = 0; k < ROWS; ++k) {
            #pragma unroll
            for (int r = 0; r < RANK; ++r)
                a[k][r] = fmaf(xp[k], g[r], a[k][r]);
            xp[k] *= x[k].x;
        }
    }

    // ---- stage 2: b[k][s] = sum_{d,r} a_pow[k][r] * G1[r][d][s]  (a folded by x1^d) ----
    #pragma unroll
    for (int k = 0; k < ROWS; ++k)
        #pragma unroll
        for (int s = 0; s < RANK; ++s) b[k][s] = 0.f;
    #pragma unroll 1
    for (int d = 0; d < D1; ++d) {
        const float* g = &sG1[d * RANK];      // g[r*64 + s]
        #pragma unroll
        for (int r = 0; r < RANK; ++r) {
            #pragma unroll
            for (int k = 0; k < ROWS; ++k)
                #pragma unroll
                for (int s = 0; s < RANK; ++s)
                    b[k][s] = fmaf(a[k][r], g[r * (D1 * RANK) + s], b[k][s]);
        }
        if (d < D1 - 1) {
            #pragma unroll
            for (int k = 0; k < ROWS; ++k)
                #pragma unroll
                for (int r = 0; r < RANK; ++r)
                    a[k][r] *= x[k].y;
        }
    }

    // ---- stage 3: a[k][t] = sum_{d,s} b_pow[k][s] * G2[s][d][t] ----
    #pragma unroll
    for (int k = 0; k < ROWS; ++k)
        #pragma unroll
        for (int r = 0; r < RANK; ++r) a[k][r] = 0.f;
    #pragma unroll 1
    for (int d = 0; d < D1; ++d) {
        const float* g = &sG2[d * RANK];
        #pragma unroll
        for (int r = 0; r < RANK; ++r) {
            #pragma unroll
            for (int k = 0; k < ROWS; ++k)
                #pragma unroll
                for (int s = 0; s < RANK; ++s)
                    a[k][s] = fmaf(b[k][r], g[r * (D1 * RANK) + s], a[k][s]);
        }
        if (d < D1 - 1) {
            #pragma unroll
            for (int k = 0; k < ROWS; ++k)
                #pragma unroll
                for (int r = 0; r < RANK; ++r)
                    b[k][r] *= x[k].z;
        }
    }

    // ---- stage 4: res[k] = sum_d x3^d * (sum_t a[k][t] * G3[t][d]) ----
    float res[ROWS];
    #pragma unroll
    for (int k = 0; k < ROWS; ++k) { res[k] = 0.f; xp[k] = 1.f; }
    #pragma unroll 1
    for (int d = 0; d < D1; ++d) {
        const float* g = &sG3T[d * RANK];     // contiguous in t
        #pragma unroll
        for (int k = 0; k < ROWS; ++k) {
            float e = 0.f;
            #pragma unroll
            for (int t = 0; t < RANK; ++t)
                e = fmaf(a[k][t], g[t], e);
            res[k] = fmaf(e, xp[k], res[k]);
            xp[k] *= x[k].w;
        }
    }

    #pragma unroll
    for (int k = 0; k < ROWS; ++k) {
        int bb = gid + k * S;
        if (bb < B) out[bb] = res[k];
    }
}

extern "C" void kernel_launch(void* const* d_in, const int* in_sizes, int n_in,
                              void* d_out, int out_size, void* d_ws, size_t ws_size,
                              hipStream_t stream) {
    const float* X  = (const float*)d_in[0];
    const float* G0 = (const float*)d_in[1];
    const float* G1 = (const float*)d_in[2];
    const float* G2 = (const float*)d_in[3];
    const float* G3 = (const float*)d_in[4];
    float* out = (float*)d_out;

    int B = in_sizes[0] / 4;   // X is [B,4]
    int block = 256;
    int grid = (B + block * ROWS - 1) / (block * ROWS);
    int S = grid * block;
    tt_poly_kernel<<<grid, block, 0, stream>>>(X, G0, G1, G2, G3, out, B, S);
}

// Round 5
// 66.383 us; speedup vs baseline: 32.0718x; 1.0012x over previous
//
#include <hip/hip_runtime.h>
#include <hip/hip_bf16.h>

#define D1 8
#define RANK 8
#define ROWS 6   // rows/thread: DS-pipe demand per sample ∝ 1/ROWS; state ~150 VGPR -> 3 waves/SIMD

__global__ __launch_bounds__(256) void tt_poly_kernel(
    const float* __restrict__ X,
    const float* __restrict__ G0,   // [d1, r]
    const float* __restrict__ G1,   // [r, d1, s]
    const float* __restrict__ G2,   // [r, d1, s]
    const float* __restrict__ G3,   // [t, d1]
    float* __restrict__ out,
    int B, int S)
{
    // G0, G1, G3 staged in LDS (2.6 KB). G2 is read straight from global with
    // wave-uniform addresses -> scalar-cache (s_load) path, off the DS pipe.
    __shared__ float sG0[D1 * RANK];          // [d][r]
    __shared__ float sG1[RANK * D1 * RANK];   // [r][d][s]
    __shared__ float sG3T[D1 * RANK];         // [d][t]

    const int tid = threadIdx.x;
    if (tid < 128)
        reinterpret_cast<float4*>(sG1)[tid] = reinterpret_cast<const float4*>(G1)[tid];
    else if (tid < 144)
        reinterpret_cast<float4*>(sG0)[tid - 128] = reinterpret_cast<const float4*>(G0)[tid - 128];
    else if (tid < 208) {
        int i = tid - 144;                    // i = t*8 + d
        sG3T[(i & 7) * RANK + (i >> 3)] = G3[i];
    }
    __syncthreads();

    const int gid = blockIdx.x * blockDim.x + tid;

    float4 x[ROWS];
    #pragma unroll
    for (int k = 0; k < ROWS; ++k) {
        int b = gid + k * S;
        x[k] = (b < B) ? reinterpret_cast<const float4*>(X)[b]
                       : make_float4(0.f, 0.f, 0.f, 0.f);
    }

    float a[ROWS][RANK];
    float b[ROWS][RANK];
    float xp[ROWS];

    // ---- stage 1: a[k][r] = sum_d x0^d * G0[d][r] ----
    #pragma unroll
    for (int k = 0; k < ROWS; ++k) {
        xp[k] = 1.f;
        #pragma unroll
        for (int r = 0; r < RANK; ++r) a[k][r] = 0.f;
    }
    #pragma unroll 1
    for (int d = 0; d < D1; ++d) {
        const float* g = &sG0[d * RANK];
        #pragma unroll
        for (int k = 0; k < ROWS; ++k) {
            #pragma unroll
            for (int r = 0; r < RANK; ++r)
                a[k][r] = fmaf(xp[k], g[r], a[k][r]);
            xp[k] *= x[k].x;
        }
    }

    // ---- stage 2: b[k][s] = sum_{d,r} (a[k][r] x1^d) * G1[r][d][s]  (LDS) ----
    #pragma unroll
    for (int k = 0; k < ROWS; ++k)
        #pragma unroll
        for (int s = 0; s < RANK; ++s) b[k][s] = 0.f;
    #pragma unroll 1
    for (int d = 0; d < D1; ++d) {
        const float* g = &sG1[d * RANK];      // g[r*(D1*RANK) + s]
        #pragma unroll
        for (int r = 0; r < RANK; ++r) {
            #pragma unroll
            for (int k = 0; k < ROWS; ++k)
                #pragma unroll
                for (int s = 0; s < RANK; ++s)
                    b[k][s] = fmaf(a[k][r], g[r * (D1 * RANK) + s], b[k][s]);
        }
        if (d < D1 - 1) {
            #pragma unroll
            for (int k = 0; k < ROWS; ++k)
                #pragma unroll
                for (int r = 0; r < RANK; ++r)
                    a[k][r] *= x[k].y;
        }
    }

    // ---- stage 3: a[k][t] = sum_{d,s} (b[k][s] x2^d) * G2[s][d][t]  (global/scalar path) ----
    #pragma unroll
    for (int k = 0; k < ROWS; ++k)
        #pragma unroll
        for (int r = 0; r < RANK; ++r) a[k][r] = 0.f;
    #pragma unroll 1
    for (int d = 0; d < D1; ++d) {
        const float* g = &G2[d * RANK];       // wave-uniform -> s_load
        #pragma unroll
        for (int r = 0; r < RANK; ++r) {
            #pragma unroll
            for (int k = 0; k < ROWS; ++k)
                #pragma unroll
                for (int s = 0; s < RANK; ++s)
                    a[k][s] = fmaf(b[k][r], g[r * (D1 * RANK) + s], a[k][s]);
        }
        if (d < D1 - 1) {
            #pragma unroll
            for (int k = 0; k < ROWS; ++k)
                #pragma unroll
                for (int r = 0; r < RANK; ++r)
                    b[k][r] *= x[k].z;
        }
    }

    // ---- stage 4: res[k] = sum_d x3^d * (sum_t a[k][t] * G3[t][d]) ----
    float res[ROWS];
    #pragma unroll
    for (int k = 0; k < ROWS; ++k) { res[k] = 0.f; xp[k] = 1.f; }
    #pragma unroll 1
    for (int d = 0; d < D1; ++d) {
        const float* g = &sG3T[d * RANK];     // contiguous in t
        #pragma unroll
        for (int k = 0; k < ROWS; ++k) {
            float e = 0.f;
            #pragma unroll
            for (int t = 0; t < RANK; ++t)
                e = fmaf(a[k][t], g[t], e);
            res[k] = fmaf(e, xp[k], res[k]);
            xp[k] *= x[k].w;
        }
    }

    #pragma unroll
    for (int k = 0; k < ROWS; ++k) {
        int bb = gid + k * S;
        if (bb < B) out[bb] = res[k];
    }
}

extern "C" void kernel_launch(void* const* d_in, const int* in_sizes, int n_in,
                              void* d_out, int out_size, void* d_ws, size_t ws_size,
                              hipStream_t stream) {
    const float* X  = (const float*)d_in[0];
    const float* G0 = (const float*)d_in[1];
    const float* G1 = (const float*)d_in[2];
    const float* G2 = (const float*)d_in[3];
    const float* G3 = (const float*)d_in[4];
    float* out = (float*)d_out;

    int B = in_sizes[0] / 4;   // X is [B,4]
    int block = 256;
    int grid = (B + block * ROWS - 1) / (block * ROWS);
    int S = grid * block;
    tt_poly_kernel<<<grid, block, 0, stream>>>(X, G0, G1, G2, G3, out, B, S);
}